// Round 2
// baseline (120.641 us; speedup 1.0000x reference)
//
#include <hip/hip_runtime.h>
#include <hip/hip_bf16.h>

using f32x4 = __attribute__((ext_vector_type(4))) float;
using s16x8 = __attribute__((ext_vector_type(8))) short;

constexpr int KDIM = 768;
constexpr int NDIM = 768;
constexpr int BM = 128;
constexpr int BN = 128;
constexpr int BK = 64;
constexpr int KLD = BK + 8;     // 72 elems: row stride 144 B -> uniform bank spread
constexpr int NT2 = KDIM / BK;  // 12 k-iterations
constexpr int NKT = KDIM / 32;  // 24 fragment k-tiles (MFMA K=32)
constexpr int N16 = NDIM / 16;  // 48 fragment n-tiles

__device__ __forceinline__ unsigned short f2bf(float f) {
    __bf16 h = (__bf16)f;       // compiler lowers pairs to v_cvt_pk_bf16_f32
    return __builtin_bit_cast(unsigned short, h);
}

// ---- pre-pass: Wf[((n16*24 + kt)*64 + lane)*8 + j] = sign(W[n16*16+(lane&15)][kt*32+(lane>>4)*8+j]) as bf16
__global__ void binarize_w(const float* __restrict__ W, unsigned short* __restrict__ Wf) {
    const int g = blockIdx.x * 256 + threadIdx.x;   // 48*24*64 = 73728 threads
    const int lane = g & 63;
    const int grp  = g >> 6;
    const int kt   = grp % NKT;
    const int n16  = grp / NKT;
    const int col  = n16 * 16 + (lane & 15);
    const int k0   = kt * 32 + (lane >> 4) * 8;
    const float* src = W + (size_t)col * KDIM + k0;
    s16x8 r;
    #pragma unroll
    for (int j = 0; j < 8; ++j) {
        float w = src[j];
        unsigned u = __builtin_bit_cast(unsigned, w);
        r[j] = (w != 0.f) ? (short)(unsigned short)(0x3F80u | ((u >> 16) & 0x8000u))
                          : (short)0;
    }
    *(s16x8*)(Wf + (size_t)g * 8) = r;
}

template<bool PRE>
__global__ __launch_bounds__(256, 2)
void binlin_mfma(const float* __restrict__ X, const float* __restrict__ W,
                 const unsigned short* __restrict__ Wf, float* __restrict__ Out) {
    __shared__ __align__(16) unsigned short As[2][BM][KLD];   // 36.9 KB, A only

    const int nbn = NDIM / BN;   // 6
    const int bid = blockIdx.x;
    const int cpx = gridDim.x >> 3;                 // 1536 % 8 == 0 -> bijective
    const int swz = (bid & 7) * cpx + (bid >> 3);
    const int bm = swz / nbn;
    const int bn = swz - bm * nbn;

    const int t    = threadIdx.x;
    const int lane = t & 63;
    const int wid  = t >> 6;
    const int wm   = (wid >> 1) * 64;
    const int wn   = (wid & 1) * 64;
    const int lr   = lane & 15;
    const int lk   = (lane >> 4) * 8;

    const float* Xb = X + (size_t)bm * BM * KDIM;
    const int srow = t >> 1;          // staging: each thread owns 32 consecutive k of one row
    const int scol = (t & 1) * 32;

    f32x4 acc[4][4] = {};

    // ---- prologue: stage k-tile 0 ----
    {
        const float* p = Xb + (size_t)srow * KDIM + scol;
        float4 a[8];
        #pragma unroll
        for (int i = 0; i < 8; ++i) a[i] = *(const float4*)(p + i * 4);
        #pragma unroll
        for (int i = 0; i < 4; ++i) {
            s16x8 c;
            c[0] = (short)f2bf(a[2*i].x);   c[1] = (short)f2bf(a[2*i].y);
            c[2] = (short)f2bf(a[2*i].z);   c[3] = (short)f2bf(a[2*i].w);
            c[4] = (short)f2bf(a[2*i+1].x); c[5] = (short)f2bf(a[2*i+1].y);
            c[6] = (short)f2bf(a[2*i+1].z); c[7] = (short)f2bf(a[2*i+1].w);
            *(s16x8*)&As[0][srow][scol + i * 8] = c;
        }
    }
    __syncthreads();

    const int fb = bn * 8 + (wn >> 4);   // base n16 index for this wave

    for (int kt = 0; kt < NT2; ++kt) {
        const int buf = kt & 1;
        const bool pf = (kt + 1 < NT2);

        // async-STAGE: issue next A tile's global loads first
        float4 a[8];
        if (pf) {
            const float* p = Xb + (size_t)srow * KDIM + (kt + 1) * BK + scol;
            #pragma unroll
            for (int i = 0; i < 8; ++i) a[i] = *(const float4*)(p + i * 4);
        }

        // B fragments straight from global (L2-resident, fragment-ordered)
        s16x8 bf_[2][4];
        #pragma unroll
        for (int kk = 0; kk < 2; ++kk)
            #pragma unroll
            for (int n = 0; n < 4; ++n) {
                if (PRE) {
                    const size_t idx = ((size_t)((fb + n) * NKT + (kt * 2 + kk)) * 64 + lane) * 8;
                    bf_[kk][n] = *(const s16x8*)(Wf + idx);
                } else {
                    const int col = bn * BN + wn + n * 16 + lr;
                    const int k0  = (kt * 2 + kk) * 32 + lk;
                    const float* wp = W + (size_t)col * KDIM + k0;
                    float4 w0 = *(const float4*)wp, w1 = *(const float4*)(wp + 4);
                    float ww[8] = {w0.x, w0.y, w0.z, w0.w, w1.x, w1.y, w1.z, w1.w};
                    s16x8 r;
                    #pragma unroll
                    for (int j = 0; j < 8; ++j) {
                        unsigned u = __builtin_bit_cast(unsigned, ww[j]);
                        r[j] = (ww[j] != 0.f) ? (short)(unsigned short)(0x3F80u | ((u >> 16) & 0x8000u))
                                              : (short)0;
                    }
                    bf_[kk][n] = r;
                }
            }

        // A fragments from LDS
        s16x8 af[2][4];
        #pragma unroll
        for (int kk = 0; kk < 2; ++kk)
            #pragma unroll
            for (int m = 0; m < 4; ++m)
                af[kk][m] = *(const s16x8*)&As[buf][wm + m * 16 + lr][kk * 32 + lk];

        #pragma unroll
        for (int kk = 0; kk < 2; ++kk)
            #pragma unroll
            for (int m = 0; m < 4; ++m)
                #pragma unroll
                for (int n = 0; n < 4; ++n)
                    acc[m][n] = __builtin_amdgcn_mfma_f32_16x16x32_bf16(
                        af[kk][m], bf_[kk][n], acc[m][n], 0, 0, 0);

        // write-late: convert + ds_write the prefetched tile
        if (pf) {
            const int nb = buf ^ 1;
            #pragma unroll
            for (int i = 0; i < 4; ++i) {
                s16x8 c;
                c[0] = (short)f2bf(a[2*i].x);   c[1] = (short)f2bf(a[2*i].y);
                c[2] = (short)f2bf(a[2*i].z);   c[3] = (short)f2bf(a[2*i].w);
                c[4] = (short)f2bf(a[2*i+1].x); c[5] = (short)f2bf(a[2*i+1].y);
                c[6] = (short)f2bf(a[2*i+1].z); c[7] = (short)f2bf(a[2*i+1].w);
                *(s16x8*)&As[nb][srow][scol + i * 8] = c;
            }
        }
        __syncthreads();
    }

    // ---- epilogue: C/D layout col = lane&15, row = (lane>>4)*4 + reg ----
    float* Ob = Out + (size_t)(bm * BM) * NDIM + bn * BN;
    #pragma unroll
    for (int m = 0; m < 4; ++m) {
        const int row0 = wm + m * 16 + (lane >> 4) * 4;
        #pragma unroll
        for (int n = 0; n < 4; ++n) {
            const int col = wn + n * 16 + lr;
            #pragma unroll
            for (int r = 0; r < 4; ++r)
                Ob[(size_t)(row0 + r) * NDIM + col] = acc[m][n][r];
        }
    }
}

extern "C" void kernel_launch(void* const* d_in, const int* in_sizes, int n_in,
                              void* d_out, int out_size, void* d_ws, size_t ws_size,
                              hipStream_t stream) {
    const float* X = (const float*)d_in[0];
    const float* W = (const float*)d_in[1];
    float* Out = (float*)d_out;
    const int M = in_sizes[0] / KDIM;                  // 32768
    const int grid = (M / BM) * (NDIM / BN);           // 1536
    const size_t need = (size_t)NDIM * KDIM * sizeof(unsigned short);  // 1.18 MB

    if (ws_size >= need) {
        unsigned short* Wf = (unsigned short*)d_ws;
        binarize_w<<<(N16 * NKT * 64) / 256, 256, 0, stream>>>(W, Wf);
        binlin_mfma<true><<<grid, 256, 0, stream>>>(X, W, Wf, Out);
    } else {
        binlin_mfma<false><<<grid, 256, 0, stream>>>(X, W, nullptr, Out);
    }
}

// Round 3
// 105.652 us; speedup vs baseline: 1.1419x; 1.1419x over previous
//
#include <hip/hip_runtime.h>
#include <hip/hip_bf16.h>

using f32x4 = __attribute__((ext_vector_type(4))) float;
using s16x8 = __attribute__((ext_vector_type(8))) short;

constexpr int KDIM = 768;
constexpr int NDIM = 768;
constexpr int BM = 128;
constexpr int BN = 128;
constexpr int BK = 64;
constexpr int NT = KDIM / BK;   // 12 k-iterations
constexpr int NKT = KDIM / 32;  // 24 fragment k-tiles (MFMA K=32)
constexpr int N16 = NDIM / 16;  // 48 fragment n-tiles

__device__ __forceinline__ unsigned short f2bf(float f) {
    __bf16 h = (__bf16)f;       // pairs lower to v_cvt_pk_bf16_f32
    return __builtin_bit_cast(unsigned short, h);
}

__device__ __forceinline__ short sgnbf(float w) {
    unsigned u = __builtin_bit_cast(unsigned, w);
    return (w != 0.f) ? (short)(unsigned short)(0x3F80u | ((u >> 16) & 0x8000u))
                      : (short)0;
}

// Wf[((n16*NKT + kt)*64 + lane)*8 + j] = sign(W[n16*16+(lane&15)][kt*32+(lane>>4)*8+j]) as bf16
__global__ void binarize_w(const float* __restrict__ W, unsigned short* __restrict__ Wf) {
    const int g = blockIdx.x * 256 + threadIdx.x;   // 48*24*64 = 73728 threads
    const int lane = g & 63;
    const int grp  = g >> 6;
    const int kt   = grp % NKT;
    const int n16  = grp / NKT;
    const int col  = n16 * 16 + (lane & 15);
    const int k0   = kt * 32 + (lane >> 4) * 8;
    const float* src = W + (size_t)col * KDIM + k0;
    s16x8 r;
    #pragma unroll
    for (int j = 0; j < 8; ++j) r[j] = sgnbf(src[j]);
    *(s16x8*)(Wf + (size_t)g * 8) = r;
}

// LDS fragment-ordered: slot = (kk*8 + sub16)*64 + lane, 16 bytes per slot.
// element(slot, j) = T[sub16*16 + (lane&15)][kt*64 + kk*32 + (lane>>4)*8 + j]
template<bool PRE>
__global__ __launch_bounds__(256, 2)
void binlin_mfma(const float* __restrict__ X, const float* __restrict__ W,
                 const unsigned short* __restrict__ Wf, float* __restrict__ Out) {
    __shared__ __align__(16) unsigned short As[2][2 * 8 * 64 * 8];  // 2 x 16 KB
    __shared__ __align__(16) unsigned short Bs[2][2 * 8 * 64 * 8];  // 2 x 16 KB

    const int nbn = NDIM / BN;   // 6
    const int bid = blockIdx.x;
    const int cpx = gridDim.x >> 3;                 // 1536 % 8 == 0 -> bijective
    const int swz = (bid & 7) * cpx + (bid >> 3);   // same-XCD chunks; bn fastest
    const int bm = swz / nbn;
    const int bn = swz - bm * nbn;

    const int t    = threadIdx.x;
    const int lane = t & 63;
    const int wid  = t >> 6;
    const int wm   = (wid >> 1) * 64;   // element row base of wave
    const int wn   = (wid & 1) * 64;    // element col base of wave
    const int wm16 = (wid >> 1) * 4;    // sub16 bases
    const int wn16 = (wid & 1) * 4;

    const float* Xb = X + (size_t)bm * BM * KDIM;

    // ---- staging decomposition: thread t owns LDS slots 4t..4t+3 ----
    const int skk  = t >> 7;            // kk of the 4 slots
    const int ssub = (t >> 4) & 7;      // sub16 of the 4 slots
    const int sla  = (t * 4) & 63;      // first lane; lanes sla..sla+3
    // A global: rows arow..arow+3, cols acol..acol+7 (within k-tile)
    const int arow = ssub * 16 + (sla & 15);
    const int acol = skk * 32 + (sla >> 4) * 8;

    f32x4 acc[4][4] = {};

    // ---- A stage: load 4 rows x 8 fp32 -> convert -> 4 contiguous 16B slots
    auto stageA = [&](int dstbuf, int kt) {
        const float* p = Xb + (size_t)arow * KDIM + kt * BK + acol;
        #pragma unroll
        for (int i = 0; i < 4; ++i) {
            float4 u = *(const float4*)(p + (size_t)i * KDIM);
            float4 v = *(const float4*)(p + (size_t)i * KDIM + 4);
            s16x8 c;
            c[0] = (short)f2bf(u.x); c[1] = (short)f2bf(u.y);
            c[2] = (short)f2bf(u.z); c[3] = (short)f2bf(u.w);
            c[4] = (short)f2bf(v.x); c[5] = (short)f2bf(v.y);
            c[6] = (short)f2bf(v.z); c[7] = (short)f2bf(v.w);
            *(s16x8*)&As[dstbuf][(size_t)(4 * t + i) * 8] = c;
        }
    };
    auto stageB = [&](int dstbuf, int kt) {
        if (PRE) {
            const unsigned short* q =
                Wf + ((size_t)((bn * 8 + ssub) * NKT + kt * 2 + skk) * 64 + sla) * 8;
            #pragma unroll
            for (int i = 0; i < 4; ++i)
                *(s16x8*)&Bs[dstbuf][(size_t)(4 * t + i) * 8] = *(const s16x8*)(q + i * 8);
        } else {
            const int col0 = bn * BN + ssub * 16 + (sla & 15);
            const int k0   = kt * BK + skk * 32 + ((sla >> 4) * 8);
            #pragma unroll
            for (int i = 0; i < 4; ++i) {
                const float* wp = W + (size_t)(col0 + i) * KDIM + k0;
                float4 u = *(const float4*)wp;
                float4 v = *(const float4*)(wp + 4);
                s16x8 c;
                c[0] = sgnbf(u.x); c[1] = sgnbf(u.y); c[2] = sgnbf(u.z); c[3] = sgnbf(u.w);
                c[4] = sgnbf(v.x); c[5] = sgnbf(v.y); c[6] = sgnbf(v.z); c[7] = sgnbf(v.w);
                *(s16x8*)&Bs[dstbuf][(size_t)(4 * t + i) * 8] = c;
            }
        }
    };

    // ---- prologue ----
    stageA(0, 0);
    stageB(0, 0);
    __syncthreads();

    for (int kt = 0; kt < NT; ++kt) {
        const int buf = kt & 1;
        const bool pf = (kt + 1 < NT);

        // issue next tile's global loads early (T14: latency hides under MFMA)
        float4 au[4], av[4];
        s16x8 bp[4];
        float4 bu[4], bv[4];
        if (pf) {
            const float* p = Xb + (size_t)arow * KDIM + (kt + 1) * BK + acol;
            #pragma unroll
            for (int i = 0; i < 4; ++i) {
                au[i] = *(const float4*)(p + (size_t)i * KDIM);
                av[i] = *(const float4*)(p + (size_t)i * KDIM + 4);
            }
            if (PRE) {
                const unsigned short* q =
                    Wf + ((size_t)((bn * 8 + ssub) * NKT + (kt + 1) * 2 + skk) * 64 + sla) * 8;
                #pragma unroll
                for (int i = 0; i < 4; ++i) bp[i] = *(const s16x8*)(q + i * 8);
            } else {
                const int col0 = bn * BN + ssub * 16 + (sla & 15);
                const int k0   = (kt + 1) * BK + skk * 32 + ((sla >> 4) * 8);
                #pragma unroll
                for (int i = 0; i < 4; ++i) {
                    const float* wp = W + (size_t)(col0 + i) * KDIM + k0;
                    bu[i] = *(const float4*)wp;
                    bv[i] = *(const float4*)(wp + 4);
                }
            }
        }

        // LDS -> fragments (lane-linear ds_read_b128, conflict-free)
        s16x8 af[2][4], bf_[2][4];
        #pragma unroll
        for (int kk = 0; kk < 2; ++kk) {
            #pragma unroll
            for (int m = 0; m < 4; ++m)
                af[kk][m] = *(const s16x8*)&As[buf][(size_t)((kk * 8 + wm16 + m) * 64 + lane) * 8];
            #pragma unroll
            for (int n = 0; n < 4; ++n)
                bf_[kk][n] = *(const s16x8*)&Bs[buf][(size_t)((kk * 8 + wn16 + n) * 64 + lane) * 8];
        }

        #pragma unroll
        for (int kk = 0; kk < 2; ++kk)
            #pragma unroll
            for (int m = 0; m < 4; ++m)
                #pragma unroll
                for (int n = 0; n < 4; ++n)
                    acc[m][n] = __builtin_amdgcn_mfma_f32_16x16x32_bf16(
                        af[kk][m], bf_[kk][n], acc[m][n], 0, 0, 0);

        // write-late: convert + contiguous ds_write of the prefetched tile
        if (pf) {
            const int nb = buf ^ 1;
            #pragma unroll
            for (int i = 0; i < 4; ++i) {
                s16x8 c;
                c[0] = (short)f2bf(au[i].x); c[1] = (short)f2bf(au[i].y);
                c[2] = (short)f2bf(au[i].z); c[3] = (short)f2bf(au[i].w);
                c[4] = (short)f2bf(av[i].x); c[5] = (short)f2bf(av[i].y);
                c[6] = (short)f2bf(av[i].z); c[7] = (short)f2bf(av[i].w);
                *(s16x8*)&As[nb][(size_t)(4 * t + i) * 8] = c;
            }
            if (PRE) {
                #pragma unroll
                for (int i = 0; i < 4; ++i)
                    *(s16x8*)&Bs[nb][(size_t)(4 * t + i) * 8] = bp[i];
            } else {
                #pragma unroll
                for (int i = 0; i < 4; ++i) {
                    s16x8 c;
                    c[0] = sgnbf(bu[i].x); c[1] = sgnbf(bu[i].y);
                    c[2] = sgnbf(bu[i].z); c[3] = sgnbf(bu[i].w);
                    c[4] = sgnbf(bv[i].x); c[5] = sgnbf(bv[i].y);
                    c[6] = sgnbf(bv[i].z); c[7] = sgnbf(bv[i].w);
                    *(s16x8*)&Bs[nb][(size_t)(4 * t + i) * 8] = c;
                }
            }
        }
        __syncthreads();
    }

    // ---- epilogue: C/D layout col = lane&15, row = (lane>>4)*4 + reg ----
    float* Ob = Out + (size_t)(bm * BM) * NDIM + bn * BN;
    const int lr = lane & 15;
    #pragma unroll
    for (int m = 0; m < 4; ++m) {
        const int row0 = wm + m * 16 + (lane >> 4) * 4;
        #pragma unroll
        for (int n = 0; n < 4; ++n) {
            const int col = wn + n * 16 + lr;
            #pragma unroll
            for (int r = 0; r < 4; ++r)
                Ob[(size_t)(row0 + r) * NDIM + col] = acc[m][n][r];
        }
    }
}

extern "C" void kernel_launch(void* const* d_in, const int* in_sizes, int n_in,
                              void* d_out, int out_size, void* d_ws, size_t ws_size,
                              hipStream_t stream) {
    const float* X = (const float*)d_in[0];
    const float* W = (const float*)d_in[1];
    float* Out = (float*)d_out;
    const int M = in_sizes[0] / KDIM;                  // 32768
    const int grid = (M / BM) * (NDIM / BN);           // 1536
    const size_t need = (size_t)NDIM * KDIM * sizeof(unsigned short);  // 1.18 MB

    if (ws_size >= need) {
        unsigned short* Wf = (unsigned short*)d_ws;
        binarize_w<<<(N16 * NKT * 64) / 256, 256, 0, stream>>>(W, Wf);
        binlin_mfma<true><<<grid, 256, 0, stream>>>(X, W, Wf, Out);
    } else {
        binlin_mfma<false><<<grid, 256, 0, stream>>>(X, W, nullptr, Out);
    }
}

// Round 4
// 99.792 us; speedup vs baseline: 1.2089x; 1.0587x over previous
//
#include <hip/hip_runtime.h>
#include <hip/hip_bf16.h>

using f32x4 = __attribute__((ext_vector_type(4))) float;
using s16x8 = __attribute__((ext_vector_type(8))) short;

constexpr int KDIM = 768;
constexpr int NDIM = 768;
constexpr int BM = 128;
constexpr int BN = 128;
constexpr int BK = 32;
constexpr int NT = KDIM / BK;   // 24 k-iterations (1 MFMA-K each)
constexpr int NKT = KDIM / 32;  // 24 fragment k-tiles
constexpr int N16 = NDIM / 16;  // 48 fragment n-tiles

__device__ __forceinline__ unsigned short f2bf(float f) {
    __bf16 h = (__bf16)f;       // pairs lower to v_cvt_pk_bf16_f32
    return __builtin_bit_cast(unsigned short, h);
}

__device__ __forceinline__ short sgnbf(float w) {
    unsigned u = __builtin_bit_cast(unsigned, w);
    return (w != 0.f) ? (short)(unsigned short)(0x3F80u | ((u >> 16) & 0x8000u))
                      : (short)0;
}

__device__ __forceinline__ s16x8 cvt8(float4 u, float4 v) {
    s16x8 c;
    c[0] = (short)f2bf(u.x); c[1] = (short)f2bf(u.y);
    c[2] = (short)f2bf(u.z); c[3] = (short)f2bf(u.w);
    c[4] = (short)f2bf(v.x); c[5] = (short)f2bf(v.y);
    c[6] = (short)f2bf(v.z); c[7] = (short)f2bf(v.w);
    return c;
}

// Wf[((n16*NKT + kt)*64 + lane)*8 + j] = sign(W[n16*16+(lane&15)][kt*32+(lane>>4)*8+j])
__global__ void binarize_w(const float* __restrict__ W, unsigned short* __restrict__ Wf) {
    const int g = blockIdx.x * 256 + threadIdx.x;   // 48*24*64 = 73728 threads
    const int lane = g & 63;
    const int grp  = g >> 6;
    const int kt   = grp % NKT;
    const int n16  = grp / NKT;
    const int col  = n16 * 16 + (lane & 15);
    const int k0   = kt * 32 + (lane >> 4) * 8;
    const float* src = W + (size_t)col * KDIM + k0;
    s16x8 r;
    #pragma unroll
    for (int j = 0; j < 8; ++j) r[j] = sgnbf(src[j]);
    *(s16x8*)(Wf + (size_t)g * 8) = r;
}

// A LDS: fragment-ordered slots, slot = sub16*64 + lane (512 slots x 16B = 8KB/buf)
// element(slot, j) = X[bm*128 + sub16*16 + (lane&15)][kt*32 + (lane>>4)*8 + j]
template<bool PRE>
__global__ __launch_bounds__(256, 3)
void binlin_mfma(const float* __restrict__ X, const float* __restrict__ W,
                 const unsigned short* __restrict__ Wf, float* __restrict__ Out) {
    __shared__ __align__(16) unsigned short As[2][512 * 8];   // 2 x 8 KB

    const int nbn = NDIM / BN;   // 6
    const int bid = blockIdx.x;
    const int cpx = gridDim.x >> 3;                 // 1536 % 8 == 0 -> bijective
    const int swz = (bid & 7) * cpx + (bid >> 3);   // same-XCD chunks; bn fastest
    const int bm = swz / nbn;
    const int bn = swz - bm * nbn;

    const int t    = threadIdx.x;
    const int lane = t & 63;
    const int wid  = t >> 6;
    const int wm   = (wid >> 1) * 64;
    const int wn   = (wid & 1) * 64;
    const int wm16 = (wid >> 1) * 4;
    const int wn16 = (wid & 1) * 4;

    const float* Xb = X + (size_t)bm * BM * KDIM;

    // staging: thread t owns slots {t, t+256}  (ds_write lane-stride 16B -> conflict-free)
    const int arow = (t >> 6) * 16 + (t & 15);      // slot t's row; slot t+256 -> +64
    const int acol = ((t >> 4) & 3) * 8;            // k-chunk within tile

    auto loadA = [&](int kt, float4 a[4]) {
        const float* p = Xb + (size_t)arow * KDIM + kt * BK + acol;
        a[0] = *(const float4*)p;
        a[1] = *(const float4*)(p + 4);
        a[2] = *(const float4*)(p + (size_t)64 * KDIM);
        a[3] = *(const float4*)(p + (size_t)64 * KDIM + 4);
    };
    auto writeA = [&](int buf, float4 a[4]) {
        *(s16x8*)&As[buf][(size_t)t * 8]         = cvt8(a[0], a[1]);
        *(s16x8*)&As[buf][(size_t)(t + 256) * 8] = cvt8(a[2], a[3]);
    };
    const int fb = bn * 8 + wn16;    // wave's base n16
    auto loadB = [&](int kt, s16x8 b[4]) {
        if (PRE) {
            #pragma unroll
            for (int n = 0; n < 4; ++n)
                b[n] = *(const s16x8*)(Wf + ((size_t)((fb + n) * NKT + kt) * 64 + lane) * 8);
        } else {
            #pragma unroll
            for (int n = 0; n < 4; ++n) {
                const int col = (fb + n) * 16 + (lane & 15);
                const int k0  = kt * 32 + (lane >> 4) * 8;
                const float* wp = W + (size_t)col * KDIM + k0;
                float4 u = *(const float4*)wp;
                float4 v = *(const float4*)(wp + 4);
                s16x8 c;
                c[0] = sgnbf(u.x); c[1] = sgnbf(u.y); c[2] = sgnbf(u.z); c[3] = sgnbf(u.w);
                c[4] = sgnbf(v.x); c[5] = sgnbf(v.y); c[6] = sgnbf(v.z); c[7] = sgnbf(v.w);
                b[n] = c;
            }
        }
    };

    f32x4 acc[4][4] = {};
    s16x8 bfr[4];

    // ---- prologue ----
    {
        float4 a0[4];
        loadA(0, a0);
        writeA(0, a0);
        loadB(0, bfr);
    }
    __syncthreads();

    for (int kt = 0; kt < NT; ++kt) {
        const int buf = kt & 1;
        const bool pf = (kt + 1 < NT);

        // issue next tile's global loads early (latency hides under this iter)
        float4 an[4];
        s16x8 bnx[4];
        if (pf) {
            loadA(kt + 1, an);
            loadB(kt + 1, bnx);
        }

        // A fragments from LDS (lane-linear ds_read_b128, conflict-free)
        s16x8 af[4];
        #pragma unroll
        for (int m = 0; m < 4; ++m)
            af[m] = *(const s16x8*)&As[buf][(size_t)((wm16 + m) * 64 + lane) * 8];

        #pragma unroll
        for (int m = 0; m < 4; ++m)
            #pragma unroll
            for (int n = 0; n < 4; ++n)
                acc[m][n] = __builtin_amdgcn_mfma_f32_16x16x32_bf16(
                    af[m], bfr[n], acc[m][n], 0, 0, 0);

        if (pf) {
            writeA(buf ^ 1, an);
            #pragma unroll
            for (int n = 0; n < 4; ++n) bfr[n] = bnx[n];
        }
        __syncthreads();
    }

    // ---- epilogue: C/D layout col = lane&15, row = (lane>>4)*4 + reg ----
    float* Ob = Out + (size_t)(bm * BM) * NDIM + bn * BN;
    const int lr = lane & 15;
    #pragma unroll
    for (int m = 0; m < 4; ++m) {
        const int row0 = wm + m * 16 + (lane >> 4) * 4;
        #pragma unroll
        for (int n = 0; n < 4; ++n) {
            const int col = wn + n * 16 + lr;
            #pragma unroll
            for (int r = 0; r < 4; ++r)
                Ob[(size_t)(row0 + r) * NDIM + col] = acc[m][n][r];
        }
    }
}

extern "C" void kernel_launch(void* const* d_in, const int* in_sizes, int n_in,
                              void* d_out, int out_size, void* d_ws, size_t ws_size,
                              hipStream_t stream) {
    const float* X = (const float*)d_in[0];
    const float* W = (const float*)d_in[1];
    float* Out = (float*)d_out;
    const int M = in_sizes[0] / KDIM;                  // 32768
    const int grid = (M / BM) * (NDIM / BN);           // 1536
    const size_t need = (size_t)NDIM * KDIM * sizeof(unsigned short);  // 1.18 MB

    if (ws_size >= need) {
        unsigned short* Wf = (unsigned short*)d_ws;
        binarize_w<<<(N16 * NKT * 64) / 256, 256, 0, stream>>>(W, Wf);
        binlin_mfma<true><<<grid, 256, 0, stream>>>(X, W, Wf, Out);
    } else {
        binlin_mfma<false><<<grid, 256, 0, stream>>>(X, W, nullptr, Out);
    }
}

// Round 5
// 98.153 us; speedup vs baseline: 1.2291x; 1.0167x over previous
//
#include <hip/hip_runtime.h>
#include <hip/hip_bf16.h>

using f32x4 = __attribute__((ext_vector_type(4))) float;
using s16x8 = __attribute__((ext_vector_type(8))) short;

constexpr int KDIM = 768;
constexpr int NDIM = 768;
constexpr int BM = 128;
constexpr int BN = 128;
constexpr int BK = 32;
constexpr int NT = KDIM / BK;   // 24 k-iterations
constexpr int NKT = KDIM / 32;  // 24 fragment k-tiles
constexpr int N16 = NDIM / 16;  // 48 fragment n-tiles

__device__ __forceinline__ unsigned short f2bf(float f) {
    __bf16 h = (__bf16)f;       // pairs lower to v_cvt_pk_bf16_f32
    return __builtin_bit_cast(unsigned short, h);
}

__device__ __forceinline__ short sgnbf(float w) {
    unsigned u = __builtin_bit_cast(unsigned, w);
    return (w != 0.f) ? (short)(unsigned short)(0x3F80u | ((u >> 16) & 0x8000u))
                      : (short)0;
}

__device__ __forceinline__ s16x8 cvt8(float4 u, float4 v) {
    s16x8 c;
    c[0] = (short)f2bf(u.x); c[1] = (short)f2bf(u.y);
    c[2] = (short)f2bf(u.z); c[3] = (short)f2bf(u.w);
    c[4] = (short)f2bf(v.x); c[5] = (short)f2bf(v.y);
    c[6] = (short)f2bf(v.z); c[7] = (short)f2bf(v.w);
    return c;
}

// Wf[((n16*NKT + kt)*64 + lane)*8 + j] = sign(W[n16*16+(lane&15)][kt*32+(lane>>4)*8+j])
__global__ void binarize_w(const float* __restrict__ W, unsigned short* __restrict__ Wf) {
    const int g = blockIdx.x * 256 + threadIdx.x;   // 48*24*64 = 73728 threads
    const int lane = g & 63;
    const int grp  = g >> 6;
    const int kt   = grp % NKT;
    const int n16  = grp / NKT;
    const int col  = n16 * 16 + (lane & 15);
    const int k0   = kt * 32 + (lane >> 4) * 8;
    const float* src = W + (size_t)col * KDIM + k0;
    s16x8 r;
    #pragma unroll
    for (int j = 0; j < 8; ++j) r[j] = sgnbf(src[j]);
    *(s16x8*)(Wf + (size_t)g * 8) = r;
}

// Barrier that does NOT drain vmcnt: ds ops ordered via lgkmcnt(0); register-
// destined global loads stay in flight across it (the whole point).
#define BAR_NODRAIN() do {                                        \
    asm volatile("s_waitcnt lgkmcnt(0)" ::: "memory");            \
    __builtin_amdgcn_s_barrier();                                 \
    asm volatile("" ::: "memory");                                \
} while (0)

// A LDS: fragment-ordered slots, slot = sub16*64 + lane (512 slots x 16B = 8KB/buf)
template<bool PRE>
__global__ __launch_bounds__(256, 3)
void binlin_mfma(const float* __restrict__ X, const float* __restrict__ W,
                 const unsigned short* __restrict__ Wf, float* __restrict__ Out) {
    __shared__ __align__(16) unsigned short As[2][512 * 8];   // 2 x 8 KB

    const int nbn = NDIM / BN;   // 6
    const int bid = blockIdx.x;
    const int cpx = gridDim.x >> 3;                 // 1536 % 8 == 0 -> bijective
    const int swz = (bid & 7) * cpx + (bid >> 3);   // same-XCD chunks; bn fastest
    const int bm = swz / nbn;
    const int bn = swz - bm * nbn;

    const int t    = threadIdx.x;
    const int lane = t & 63;
    const int wid  = t >> 6;
    const int wm   = (wid >> 1) * 64;
    const int wn   = (wid & 1) * 64;
    const int wm16 = (wid >> 1) * 4;
    const int wn16 = (wid & 1) * 4;

    const float* Xb = X + (size_t)bm * BM * KDIM;

    // staging: thread t owns slots {t, t+256}  (lane-stride-16B writes, 0-conflict, verified R4)
    const int arow = (t >> 6) * 16 + (t & 15);
    const int acol = ((t >> 4) & 3) * 8;
    const float* Abase = Xb + (size_t)arow * KDIM + acol;   // + kt*BK (imm after unroll)

    auto loadA = [&](int kt, float4 a[4]) {
        const float* p = Abase + kt * BK;
        a[0] = *(const float4*)p;
        a[1] = *(const float4*)(p + 4);
        a[2] = *(const float4*)(p + (size_t)64 * KDIM);
        a[3] = *(const float4*)(p + (size_t)64 * KDIM + 4);
    };
    auto writeA = [&](int buf, float4 a[4]) {
        *(s16x8*)&As[buf][(size_t)t * 8]         = cvt8(a[0], a[1]);
        *(s16x8*)&As[buf][(size_t)(t + 256) * 8] = cvt8(a[2], a[3]);
    };
    const int fb = bn * 8 + wn16;
    auto loadB = [&](int kt, s16x8 b[4]) {
        if constexpr (PRE) {
            #pragma unroll
            for (int n = 0; n < 4; ++n)
                b[n] = *(const s16x8*)(Wf + ((size_t)((fb + n) * NKT + kt) * 64 + lane) * 8);
        } else {
            #pragma unroll
            for (int n = 0; n < 4; ++n) {
                const int col = (fb + n) * 16 + (lane & 15);
                const int k0  = kt * 32 + (lane >> 4) * 8;
                const float* wp = W + (size_t)col * KDIM + k0;
                float4 u = *(const float4*)wp;
                float4 v = *(const float4*)(wp + 4);
                s16x8 c;
                c[0] = sgnbf(u.x); c[1] = sgnbf(u.y); c[2] = sgnbf(u.z); c[3] = sgnbf(u.w);
                c[4] = sgnbf(v.x); c[5] = sgnbf(v.y); c[6] = sgnbf(v.z); c[7] = sgnbf(v.w);
                b[n] = c;
            }
        }
    };

    f32x4 acc[4][4] = {};
    float4 A0[4], A1[4];
    s16x8 B0[4], B1[4];

    // ---- prologue: 2-deep ----
    loadA(0, A0);
    loadA(1, A1);
    loadB(0, B0);
    loadB(1, B1);
    writeA(0, A0);          // compiler: counted vmcnt wait for A0 only
    BAR_NODRAIN();

    #pragma unroll
    for (int kt = 0; kt < NT; ++kt) {
        const int c = kt & 1;
        float4 (&AL)[4] = c ? A1 : A0;   // dead set -> load tile kt+2
        float4 (&AW)[4] = c ? A0 : A1;   // tile kt+1 -> cvt + ds_write this iter
        s16x8 (&BC)[4]  = c ? B1 : B0;   // tile kt (consume), then reload <- kt+2

        if (kt + 2 < NT) loadA(kt + 2, AL);

        s16x8 af[4];
        #pragma unroll
        for (int m = 0; m < 4; ++m)
            af[m] = *(const s16x8*)&As[c][(size_t)((wm16 + m) * 64 + lane) * 8];

        #pragma unroll
        for (int m = 0; m < 4; ++m)
            #pragma unroll
            for (int n = 0; n < 4; ++n)
                acc[m][n] = __builtin_amdgcn_mfma_f32_16x16x32_bf16(
                    af[m], BC[n], acc[m][n], 0, 0, 0);

        if (kt + 1 < NT) writeA(c ^ 1, AW);   // vmcnt(counted): AW loaded a full iter ago
        if (kt + 2 < NT) loadB(kt + 2, BC);   // BC dead after MFMA above
        if (kt + 1 < NT) BAR_NODRAIN();
    }

    // ---- epilogue: C/D layout col = lane&15, row = (lane>>4)*4 + reg ----
    float* Ob = Out + (size_t)(bm * BM) * NDIM + bn * BN;
    const int lr = lane & 15;
    #pragma unroll
    for (int m = 0; m < 4; ++m) {
        const int row0 = wm + m * 16 + (lane >> 4) * 4;
        #pragma unroll
        for (int n = 0; n < 4; ++n) {
            const int col = wn + n * 16 + lr;
            #pragma unroll
            for (int r = 0; r < 4; ++r)
                Ob[(size_t)(row0 + r) * NDIM + col] = acc[m][n][r];
        }
    }
}

extern "C" void kernel_launch(void* const* d_in, const int* in_sizes, int n_in,
                              void* d_out, int out_size, void* d_ws, size_t ws_size,
                              hipStream_t stream) {
    const float* X = (const float*)d_in[0];
    const float* W = (const float*)d_in[1];
    float* Out = (float*)d_out;
    const int M = in_sizes[0] / KDIM;                  // 32768
    const int grid = (M / BM) * (NDIM / BN);           // 1536
    const size_t need = (size_t)NDIM * KDIM * sizeof(unsigned short);  // 1.18 MB

    if (ws_size >= need) {
        unsigned short* Wf = (unsigned short*)d_ws;
        binarize_w<<<(N16 * NKT * 64) / 256, 256, 0, stream>>>(W, Wf);
        binlin_mfma<true><<<grid, 256, 0, stream>>>(X, W, Wf, Out);
    } else {
        binlin_mfma<false><<<grid, 256, 0, stream>>>(X, W, nullptr, Out);
    }
}

// Round 6
// 60.726 us; speedup vs baseline: 1.9866x; 1.6163x over previous
//
#include <hip/hip_runtime.h>
#include <hip/hip_bf16.h>

using f32x4 = __attribute__((ext_vector_type(4))) float;
using s16x8 = __attribute__((ext_vector_type(8))) short;

constexpr int KDIM = 768;
constexpr int NDIM = 768;
constexpr int BM = 128;
constexpr int BN = 128;
constexpr int BK = 32;
constexpr int NBN = NDIM / BN;  // 6
constexpr int NT = KDIM / BK;   // 24 k-iterations

__device__ __forceinline__ unsigned short f2bf(float f) {
    __bf16 h = (__bf16)f;       // pairs lower to v_cvt_pk_bf16_f32
    return __builtin_bit_cast(unsigned short, h);
}

__device__ __forceinline__ short sgnbf(float w) {
    unsigned u = __builtin_bit_cast(unsigned, w);
    return (w != 0.f) ? (short)(unsigned short)(0x3F80u | ((u >> 16) & 0x8000u))
                      : (short)0;
}

__device__ __forceinline__ s16x8 cvt8(float4 u, float4 v) {
    s16x8 c;
    c[0] = (short)f2bf(u.x); c[1] = (short)f2bf(u.y);
    c[2] = (short)f2bf(u.z); c[3] = (short)f2bf(u.w);
    c[4] = (short)f2bf(v.x); c[5] = (short)f2bf(v.y);
    c[6] = (short)f2bf(v.z); c[7] = (short)f2bf(v.w);
    return c;
}

// Block-contiguous fragment-ordered W: for (kt, bn), an 8 KB chunk of 512
// slots x 16 B.  slot = n16l*64 + lane ; element j of slot:
//   col = bn*128 + n16l*16 + (lane&15), k = kt*32 + (lane>>4)*8 + j
__global__ void binarize_w(const float* __restrict__ W, unsigned short* __restrict__ Wf) {
    const int g = blockIdx.x * 256 + threadIdx.x;   // 24*6*8*64 = 73728 threads
    const int lane = g & 63;
    const int grp  = g >> 6;            // (kt*NBN + bn)*8 + n16l
    const int n16l = grp & 7;
    const int bkt  = grp >> 3;          // kt*NBN + bn
    const int bn   = bkt % NBN;
    const int kt   = bkt / NBN;
    const int col  = bn * 128 + n16l * 16 + (lane & 15);
    const int k0   = kt * 32 + (lane >> 4) * 8;
    const float* src = W + (size_t)col * KDIM + k0;
    s16x8 r;
    #pragma unroll
    for (int j = 0; j < 8; ++j) r[j] = sgnbf(src[j]);
    *(s16x8*)(Wf + (size_t)g * 8) = r;
}

// Barrier that does NOT drain vmcnt (ds ops ordered via lgkmcnt(0)).
#define BAR_NODRAIN() do {                                        \
    asm volatile("s_waitcnt lgkmcnt(0)" ::: "memory");            \
    __builtin_amdgcn_s_barrier();                                 \
    asm volatile("" ::: "memory");                                \
} while (0)

// LDS: fragment-ordered, slot = sub16*64 + lane, 16 B/slot, 512 slots = 8 KB/buf
template<bool PRE>
__global__ __launch_bounds__(256, 4)
void binlin_mfma(const float* __restrict__ X, const float* __restrict__ W,
                 const unsigned short* __restrict__ Wf, float* __restrict__ Out) {
    __shared__ __align__(16) unsigned short As[2][512 * 8];   // 2 x 8 KB
    __shared__ __align__(16) unsigned short Bs[2][512 * 8];   // 2 x 8 KB

    const int bid = blockIdx.x;
    const int cpx = gridDim.x >> 3;                 // 1536 % 8 == 0 -> bijective
    const int swz = (bid & 7) * cpx + (bid >> 3);   // same-XCD chunks; bn fastest
    const int bm = swz / NBN;
    const int bn = swz - bm * NBN;

    const int t    = threadIdx.x;
    const int lane = t & 63;
    const int wid  = t >> 6;
    const int wm   = (wid >> 1) * 64;
    const int wn   = (wid & 1) * 64;
    const int wm16 = (wid >> 1) * 4;
    const int wn16 = (wid & 1) * 4;

    const float* Xb = X + (size_t)bm * BM * KDIM;

    // ---- A staging: thread t reads rows {t>>2, (t>>2)+64}, k-chunk (t&3)*8.
    // Adjacent lane quads cover contiguous 128 B per row (R1's coalescing).
    const int r   = t >> 2;
    const int c8  = (t & 3) * 8;
    const float* Abase = Xb + (size_t)r * KDIM + c8;
    // frag slot for (row, chunk): sub16*64 + (row&15) + 16*chunk
    const int sA1 = (r >> 4) * 64 + (r & 15) + 16 * (t & 3);
    const int sA2 = sA1 + 256;                      // row + 64 -> sub16 + 4

    float4 aR[4];
    s16x8  bR[2];

    auto loadA = [&](int kt) {
        const float* p = Abase + kt * BK;
        aR[0] = *(const float4*)p;
        aR[1] = *(const float4*)(p + 4);
        aR[2] = *(const float4*)(p + (size_t)64 * KDIM);
        aR[3] = *(const float4*)(p + (size_t)64 * KDIM + 4);
    };
    auto writeA = [&](int buf) {
        *(s16x8*)&As[buf][(size_t)sA1 * 8] = cvt8(aR[0], aR[1]);
        *(s16x8*)&As[buf][(size_t)sA2 * 8] = cvt8(aR[2], aR[3]);
    };
    // ---- B staging: thread t owns slots {2t, 2t+1} = contiguous 32 B
    auto loadB = [&](int kt) {
        if constexpr (PRE) {
            const unsigned short* q = Wf + ((size_t)(kt * NBN + bn) * 512 + 2 * t) * 8;
            bR[0] = *(const s16x8*)q;
            bR[1] = *(const s16x8*)(q + 8);
        } else {
            #pragma unroll
            for (int i = 0; i < 2; ++i) {
                const int s    = 2 * t + i;
                const int col  = bn * 128 + (s >> 6) * 16 + (s & 15);
                const int k0   = kt * 32 + ((s >> 4) & 3) * 8;
                const float* wp = W + (size_t)col * KDIM + k0;
                float4 u = *(const float4*)wp;
                float4 v = *(const float4*)(wp + 4);
                s16x8 c;
                c[0] = sgnbf(u.x); c[1] = sgnbf(u.y); c[2] = sgnbf(u.z); c[3] = sgnbf(u.w);
                c[4] = sgnbf(v.x); c[5] = sgnbf(v.y); c[6] = sgnbf(v.z); c[7] = sgnbf(v.w);
                bR[i] = c;
            }
        }
    };
    auto writeB = [&](int buf) {
        *(s16x8*)&Bs[buf][(size_t)(2 * t) * 8]     = bR[0];
        *(s16x8*)&Bs[buf][(size_t)(2 * t + 1) * 8] = bR[1];
    };

    f32x4 acc[4][4] = {};

    // ---- prologue ----
    loadA(0); loadB(0);
    writeA(0); writeB(0);
    BAR_NODRAIN();

    #pragma unroll 2
    for (int kt = 0; kt < NT; ++kt) {
        const int c = kt & 1;
        const bool pf = (kt + 1 < NT);

        // issue-early: next tile's global loads (hide under MFMA below)
        if (pf) { loadA(kt + 1); loadB(kt + 1); }

        // fragments from LDS (lane-linear ds_read_b128, conflict-free)
        s16x8 af[4], bf_[4];
        #pragma unroll
        for (int m = 0; m < 4; ++m)
            af[m] = *(const s16x8*)&As[c][(size_t)((wm16 + m) * 64 + lane) * 8];
        #pragma unroll
        for (int n = 0; n < 4; ++n)
            bf_[n] = *(const s16x8*)&Bs[c][(size_t)((wn16 + n) * 64 + lane) * 8];

        #pragma unroll
        for (int m = 0; m < 4; ++m)
            #pragma unroll
            for (int n = 0; n < 4; ++n)
                acc[m][n] = __builtin_amdgcn_mfma_f32_16x16x32_bf16(
                    af[m], bf_[n], acc[m][n], 0, 0, 0);

        // write-late into the other buffer, one barrier per iter
        if (pf) {
            writeA(c ^ 1); writeB(c ^ 1);
            BAR_NODRAIN();
        }
    }

    // ---- epilogue: C/D layout col = lane&15, row = (lane>>4)*4 + reg ----
    float* Ob = Out + (size_t)(bm * BM) * NDIM + bn * BN;
    const int lr = lane & 15;
    #pragma unroll
    for (int m = 0; m < 4; ++m) {
        const int row0 = wm + m * 16 + (lane >> 4) * 4;
        #pragma unroll
        for (int n = 0; n < 4; ++n) {
            const int col = wn + n * 16 + lr;
            #pragma unroll
            for (int rr = 0; rr < 4; ++rr)
                Ob[(size_t)(row0 + rr) * NDIM + col] = acc[m][n][rr];
        }
    }
}

extern "C" void kernel_launch(void* const* d_in, const int* in_sizes, int n_in,
                              void* d_out, int out_size, void* d_ws, size_t ws_size,
                              hipStream_t stream) {
    const float* X = (const float*)d_in[0];
    const float* W = (const float*)d_in[1];
    float* Out = (float*)d_out;
    const int M = in_sizes[0] / KDIM;                  // 32768
    const int grid = (M / BM) * NBN;                   // 1536
    const size_t need = (size_t)NDIM * KDIM * sizeof(unsigned short);  // 1.125 MB

    if (ws_size >= need) {
        unsigned short* Wf = (unsigned short*)d_ws;
        binarize_w<<<(NT * NBN * 8 * 64) / 256, 256, 0, stream>>>(W, Wf);
        binlin_mfma<true><<<grid, 256, 0, stream>>>(X, W, Wf, Out);
    } else {
        binlin_mfma<false><<<grid, 256, 0, stream>>>(X, W, nullptr, Out);
    }
}